// Round 2
// baseline (581.632 us; speedup 1.0000x reference)
//
#include <hip/hip_runtime.h>

typedef __attribute__((ext_vector_type(4))) float floatx4;
typedef __attribute__((ext_vector_type(8))) short bf16x8;

__device__ __forceinline__ unsigned short f2bf(float f) {
    union { float f; unsigned u; } v; v.f = f;
    unsigned r = v.u + 0x7fffu + ((v.u >> 16) & 1u);  // RNE
    return (unsigned short)(r >> 16);
}

// ---------------------------------------------------------------------------
// prep: pack weights into MFMA B-operand fragment blobs (bf16) + fuse biases.
// Wcat blob [kc=0..47][ntg=0..31][lane=0..63][j=0..7]:
//   element B[k][n], k = kc*32 + (lane>>4)*8 + j, n = ntg*16 + (lane&15)
//   k < 1024 -> W1[c][k][s] (c=n>>5, s=n&31), else W2[c][k-1024][s]
// W3 blob   [kc=0..15][ntg=0..31][lane][j]: B[k][n] = W3flat[k*512 + n]
// bias12[n] = b1flat[n] + b2flat[n];  bias3s[n] = sum_c b3[c*512+n]
// ---------------------------------------------------------------------------
__global__ void prep_kernel(const float* __restrict__ W1, const float* __restrict__ b1,
                            const float* __restrict__ W2, const float* __restrict__ b2,
                            const float* __restrict__ W3, const float* __restrict__ b3,
                            unsigned short* __restrict__ wcat, unsigned short* __restrict__ w3f,
                            float* __restrict__ bias12, float* __restrict__ bias3s)
{
    int tid = blockIdx.x * 256 + threadIdx.x;
    if (tid < 98304) {                       // 48 * 32 * 64 fragment-lanes
        int l  = tid & 63;
        int nt = (tid >> 6) & 31;
        int kc = tid >> 11;                  // 0..47
        int n  = nt * 16 + (l & 15);
        int k0 = kc * 32 + ((l >> 4) << 3);
        int c = n >> 5, s = n & 31;
        union { unsigned short us[8]; int4 v; } pk;
        const float* src = (k0 < 1024) ? (W1 + c * 32768 + k0 * 32 + s)
                                       : (W2 + c * 16384 + (k0 - 1024) * 32 + s);
        #pragma unroll
        for (int j = 0; j < 8; ++j) pk.us[j] = f2bf(src[j * 32]);
        *(int4*)(wcat + (size_t)tid * 8) = pk.v;
    } else if (tid < 131072) {               // 16 * 32 * 64 fragment-lanes for W3
        int t  = tid - 98304;
        int l  = t & 63;
        int nt = (t >> 6) & 31;
        int kc = t >> 11;                    // 0..15
        int n  = nt * 16 + (l & 15);
        int k0 = kc * 32 + ((l >> 4) << 3);
        union { unsigned short us[8]; int4 v; } pk;
        const float* src = W3 + k0 * 512 + n;
        #pragma unroll
        for (int j = 0; j < 8; ++j) pk.us[j] = f2bf(src[j * 512]);
        *(int4*)(w3f + (size_t)t * 8) = pk.v;
    } else if (tid < 131584) {
        int n = tid - 131072;
        bias12[n] = b1[n] + b2[n];
        float sacc = 0.f;
        #pragma unroll
        for (int c = 0; c < 16; ++c) sacc += b3[c * 512 + n];
        bias3s[n] = sacc;
    }
}

// ---------------------------------------------------------------------------
// fused main: per block 64 rows, 512 threads = 8 waves, wave w owns cols
// [w*64, w*64+64). Cross-barrier software pipeline:
//  - raw s_barrier + manual lgkmcnt(0) (NO vmcnt drain -> global prefetches
//    stay in flight across barriers, unlike __syncthreads()).
//  - B-fragments reloaded IN PLACE right after their last MFMA use
//    (~1 full iteration of L2-latency cover, zero extra VGPRs).
//  - A-chunk (HBM) issued 2 iterations ahead into a register pair.
//  - phase-3 W3 fragments for kc=0 issued BEFORE the phase-2 barrier.
// Dbuf race safety: each wave's lgkmcnt(0) before a barrier drains its own
// ds_reads of buffer X; buffer X is only rewritten after that barrier.
// MFMA 16x16x32 bf16; A-frag: lane l holds A[m=l&15][k=(l>>4)*8+j];
// B-frag: B[k=(l>>4)*8+j][n=l&15]; C/D: col=l&15, row=(l>>4)*4+reg.
// ---------------------------------------------------------------------------
__global__ __launch_bounds__(512, 4) void fused_main(
    const float* __restrict__ app, const float* __restrict__ sp,
    const unsigned short* __restrict__ wcat, const unsigned short* __restrict__ w3f,
    const float* __restrict__ bias12, const float* __restrict__ bias3s,
    float* __restrict__ out)
{
    __shared__ unsigned short As[2][4][64][8];   // 8 KB  A-frag staging (dbuf)
    __shared__ unsigned short Hf[4][16][64][8];  // 64 KB H in A-frag layout

    const int tid = (int)threadIdx.x;
    const int w   = tid >> 6;                 // 0..7
    const int l   = tid & 63;
    const int rowbase = (int)blockIdx.x * 64;

    // cooperative A-staging mapping: thread -> (row sr, 4-wide k-chunk scc)
    const int sr  = tid >> 3;                 // 0..63
    const int scc = tid & 7;                  // 0..7
    const float* appsrc = app + (size_t)(rowbase + sr) * 1024 + scc * 4;
    const float* spsrc  = sp  + (size_t)(rowbase + sr) * 512  + scc * 4;
    unsigned short* as0 = &As[0][sr >> 4][(scc >> 1) * 16 + (sr & 15)][(scc & 1) * 4];
    unsigned short* as1 = &As[1][sr >> 4][(scc >> 1) * 16 + (sr & 15)][(scc & 1) * 4];

    floatx4 acc[4][4];
    #pragma unroll
    for (int mt = 0; mt < 4; ++mt)
        #pragma unroll
        for (int nt = 0; nt < 4; ++nt)
            acc[mt][nt] = (floatx4){0.f, 0.f, 0.f, 0.f};

    // prologue: stage chunk 0 -> As[0]; load chunk 1; load bfrag(kb=0)
    {
        float4 p = *(const float4*)(appsrc);
        union { unsigned short us[4]; int2 v; } pk;
        pk.us[0] = f2bf(p.x); pk.us[1] = f2bf(p.y);
        pk.us[2] = f2bf(p.z); pk.us[3] = f2bf(p.w);
        *(int2*)as0 = pk.v;
    }
    float4 pA = *(const float4*)(appsrc + 32);   // chunk 1 (HBM)

    const unsigned short* wbase = wcat + (size_t)w * 2048 + (size_t)l * 8;
    bf16x8 bcur[4];
    #pragma unroll
    for (int nt = 0; nt < 4; ++nt)
        bcur[nt] = *(const bf16x8*)(wbase + nt * 512);

    asm volatile("s_waitcnt lgkmcnt(0)" ::: "memory");
    __builtin_amdgcn_s_barrier();
    asm volatile("" ::: "memory");

    // ---- phase 1: H_pre = [app|sp] @ Wcat, K = 1536 (48 chunks of 32) ----
    for (int kb = 0; kb < 48; ++kb) {
        // A-fragments for THIS iteration (buffer ready since last barrier)
        bf16x8 af[4];
        #pragma unroll
        for (int mt = 0; mt < 4; ++mt)
            af[mt] = *(const bf16x8*)(&As[kb & 1][mt][l][0]);

        // issue HBM load 2 chunks ahead
        float4 pB;
        if (kb + 2 < 48) {
            const float* src = (kb + 2 < 32) ? (appsrc + (kb + 2) * 32)
                                             : (spsrc + (kb - 30) * 32);
            pB = *(const float4*)src;
        }

        // stage chunk kb+1 (loaded 2 iters ago, vmcnt long since covered)
        if (kb + 1 < 48) {
            union { unsigned short us[4]; int2 v; } pk;
            pk.us[0] = f2bf(pA.x); pk.us[1] = f2bf(pA.y);
            pk.us[2] = f2bf(pA.z); pk.us[3] = f2bf(pA.w);
            *(int2*)(((kb & 1) == 0) ? as1 : as0) = pk.v;
        }

        // MFMA; reload each B-frag in place right after its last use so the
        // L2 load for kb+1 has ~a full iteration in flight (crosses barrier)
        const unsigned short* wp = wbase + (size_t)(kb + 1) * 16384;
        #pragma unroll
        for (int nt = 0; nt < 4; ++nt) {
            #pragma unroll
            for (int mt = 0; mt < 4; ++mt)
                acc[mt][nt] = __builtin_amdgcn_mfma_f32_16x16x32_bf16(
                    af[mt], bcur[nt], acc[mt][nt], 0, 0, 0);
            if (kb + 1 < 48)
                bcur[nt] = *(const bf16x8*)(wp + nt * 512);
        }

        pA = pB;

        if (kb + 1 < 48) {
            asm volatile("s_waitcnt lgkmcnt(0)" ::: "memory");
            __builtin_amdgcn_s_barrier();
            asm volatile("" ::: "memory");
        }
    }

    // ---- phase 3 prefetch (issued BEFORE phase-2 barrier; vmcnt survives) --
    const unsigned short* w3base = w3f + (size_t)w * 2048 + (size_t)l * 8;
    bf16x8 b3[4];
    #pragma unroll
    for (int nt = 0; nt < 4; ++nt)
        b3[nt] = *(const bf16x8*)(w3base + nt * 512);

    // ---- phase 2: relu + bias, write Hf in A-frag layout ----
    #pragma unroll
    for (int nt = 0; nt < 4; ++nt) {
        const int colg = w * 64 + nt * 16 + (l & 15);
        const float bv = bias12[colg];
        const int kc  = colg >> 5;
        const int lhi = ((colg >> 3) & 3) << 4;
        const int j   = colg & 7;
        #pragma unroll
        for (int mt = 0; mt < 4; ++mt)
            #pragma unroll
            for (int r = 0; r < 4; ++r) {
                const int rlow = ((l >> 4) << 2) + r;      // rowg & 15
                float v = acc[mt][nt][r] + bv;
                v = fmaxf(v, 0.f);
                Hf[mt][kc][lhi + rlow][j] = f2bf(v);
            }
    }
    asm volatile("s_waitcnt lgkmcnt(0)" ::: "memory");
    __builtin_amdgcn_s_barrier();
    asm volatile("" ::: "memory");

    // ---- phase 3: out = relu(Hf @ W3 + bias3s), K = 512 ----
    #pragma unroll
    for (int mt = 0; mt < 4; ++mt)
        #pragma unroll
        for (int nt = 0; nt < 4; ++nt)
            acc[mt][nt] = (floatx4){0.f, 0.f, 0.f, 0.f};

    for (int kc = 0; kc < 16; ++kc) {
        bf16x8 af[4];
        #pragma unroll
        for (int mt = 0; mt < 4; ++mt)
            af[mt] = *(const bf16x8*)(&Hf[mt][kc][l][0]);
        const unsigned short* wp = w3base + (size_t)(kc + 1) * 16384;
        #pragma unroll
        for (int nt = 0; nt < 4; ++nt) {
            #pragma unroll
            for (int mt = 0; mt < 4; ++mt)
                acc[mt][nt] = __builtin_amdgcn_mfma_f32_16x16x32_bf16(
                    af[mt], b3[nt], acc[mt][nt], 0, 0, 0);
            if (kc + 1 < 16)
                b3[nt] = *(const bf16x8*)(wp + nt * 512);
        }
    }

    // ---- epilogue ----
    #pragma unroll
    for (int nt = 0; nt < 4; ++nt) {
        const int colg = w * 64 + nt * 16 + (l & 15);
        const float bv = bias3s[colg];
        #pragma unroll
        for (int mt = 0; mt < 4; ++mt)
            #pragma unroll
            for (int r = 0; r < 4; ++r) {
                const int rowg = mt * 16 + ((l >> 4) << 2) + r;
                float v = acc[mt][nt][r] + bv;
                v = fmaxf(v, 0.f);
                out[(size_t)(rowbase + rowg) * 512 + colg] = v;
            }
    }
}

extern "C" void kernel_launch(void* const* d_in, const int* in_sizes, int n_in,
                              void* d_out, int out_size, void* d_ws, size_t ws_size,
                              hipStream_t stream)
{
    const float* app = (const float*)d_in[0];
    const float* sp  = (const float*)d_in[1];
    const float* W1  = (const float*)d_in[2];
    const float* b1  = (const float*)d_in[3];
    const float* W2  = (const float*)d_in[4];
    const float* b2  = (const float*)d_in[5];
    const float* W3  = (const float*)d_in[6];
    const float* b3  = (const float*)d_in[7];

    char* ws = (char*)d_ws;
    unsigned short* wcat  = (unsigned short*)(ws);             // 1,572,864 B
    unsigned short* w3f   = (unsigned short*)(ws + 1572864);   //   524,288 B
    float*          b12   = (float*)(ws + 2097152);            //     2,048 B
    float*          b3s   = (float*)(ws + 2099200);            //     2,048 B

    prep_kernel<<<514, 256, 0, stream>>>(W1, b1, W2, b2, W3, b3, wcat, w3f, b12, b3s);

    float* outp = (float*)d_out;
    fused_main<<<65536 / 64, 512, 0, stream>>>(app, sp, wcat, w3f, b12, b3s, outp);
}

// Round 3
// 542.850 us; speedup vs baseline: 1.0714x; 1.0714x over previous
//
#include <hip/hip_runtime.h>

typedef __attribute__((ext_vector_type(4))) float floatx4;
typedef __attribute__((ext_vector_type(8))) short bf16x8;

__device__ __forceinline__ unsigned short f2bf(float f) {
    union { float f; unsigned u; } v; v.f = f;
    unsigned r = v.u + 0x7fffu + ((v.u >> 16) & 1u);  // RNE
    return (unsigned short)(r >> 16);
}

// ---------------------------------------------------------------------------
// prep: pack weights into MFMA B-operand fragment blobs (bf16) + fuse biases.
// Wcat blob [kc=0..47][ntg=0..31][lane=0..63][j=0..7]:
//   element B[k][n], k = kc*32 + (lane>>4)*8 + j, n = ntg*16 + (lane&15)
//   k < 1024 -> W1[c][k][s] (c=n>>5, s=n&31), else W2[c][k-1024][s]
// W3 blob   [kc=0..15][ntg=0..31][lane][j]: B[k][n] = W3flat[k*512 + n]
// bias12[n] = b1flat[n] + b2flat[n];  bias3s[n] = sum_c b3[c*512+n]
// ---------------------------------------------------------------------------
__global__ void prep_kernel(const float* __restrict__ W1, const float* __restrict__ b1,
                            const float* __restrict__ W2, const float* __restrict__ b2,
                            const float* __restrict__ W3, const float* __restrict__ b3,
                            unsigned short* __restrict__ wcat, unsigned short* __restrict__ w3f,
                            float* __restrict__ bias12, float* __restrict__ bias3s)
{
    int tid = blockIdx.x * 256 + threadIdx.x;
    if (tid < 98304) {                       // 48 * 32 * 64 fragment-lanes
        int l  = tid & 63;
        int nt = (tid >> 6) & 31;
        int kc = tid >> 11;                  // 0..47
        int n  = nt * 16 + (l & 15);
        int k0 = kc * 32 + ((l >> 4) << 3);
        int c = n >> 5, s = n & 31;
        union { unsigned short us[8]; int4 v; } pk;
        const float* src = (k0 < 1024) ? (W1 + c * 32768 + k0 * 32 + s)
                                       : (W2 + c * 16384 + (k0 - 1024) * 32 + s);
        #pragma unroll
        for (int j = 0; j < 8; ++j) pk.us[j] = f2bf(src[j * 32]);
        *(int4*)(wcat + (size_t)tid * 8) = pk.v;
    } else if (tid < 131072) {               // 16 * 32 * 64 fragment-lanes for W3
        int t  = tid - 98304;
        int l  = t & 63;
        int nt = (t >> 6) & 31;
        int kc = t >> 11;                    // 0..15
        int n  = nt * 16 + (l & 15);
        int k0 = kc * 32 + ((l >> 4) << 3);
        union { unsigned short us[8]; int4 v; } pk;
        const float* src = W3 + k0 * 512 + n;
        #pragma unroll
        for (int j = 0; j < 8; ++j) pk.us[j] = f2bf(src[j * 512]);
        *(int4*)(w3f + (size_t)t * 8) = pk.v;
    } else if (tid < 131584) {
        int n = tid - 131072;
        bias12[n] = b1[n] + b2[n];
        float sacc = 0.f;
        #pragma unroll
        for (int c = 0; c < 16; ++c) sacc += b3[c * 512 + n];
        bias3s[n] = sacc;
    }
}

// ---------------------------------------------------------------------------
// fused main: 64 rows/block, 512 threads = 8 waves, wave w owns cols
// [w*64, w*64+64). Restructured to BK=64 periods (24 in phase 1):
//  - ONE raw barrier per period (lgkmcnt(0) only; vmcnt survives barriers).
//  - all 8 B-frags for p+1 reloaded in a batch AFTER the MFMA clusters
//    (compiler emits counted vmcnt at next use, never 0).
//  - A-chunk (HBM) issued at top of period p for p+1, staged at tail.
//  - phase 3 has NO barriers (Hf read-only); W3 frags prefetched before
//    the phase-2 barrier.
//  - LDS: As (16 KB) unioned over the head of Hf (64 KB) -> 65536 B total,
//    2 blocks/CU. As is dead once phase-2 writes begin (all reads drained
//    at the final phase-1 barrier).
// MFMA 16x16x32 bf16; A-frag: lane l holds A[m=l&15][k=(l>>4)*8+j];
// B-frag: B[k=(l>>4)*8+j][n=l&15]; C/D: col=l&15, row=(l>>4)*4+reg.
// A-frag staging map: thread (sr=tid>>3, kq=tid&7) packs 8 floats of row sr,
// k = p*64 + kq*8 .. +7 into As[buf][kq>>2][sr>>4][(kq&3)*16+(sr&15)][0..7].
// ---------------------------------------------------------------------------
__global__ __launch_bounds__(512, 4) void fused_main(
    const float* __restrict__ app, const float* __restrict__ sp,
    const unsigned short* __restrict__ wcat, const unsigned short* __restrict__ w3f,
    const float* __restrict__ bias12, const float* __restrict__ bias3s,
    float* __restrict__ out)
{
    __shared__ union {
        unsigned short As[2][2][4][64][8];   // 16 KB: [buf][half][mt][lane][j]
        unsigned short Hf[4][16][64][8];     // 64 KB: [mt][kc][lane][j]
    } sh;

    const int tid = (int)threadIdx.x;
    const int w   = tid >> 6;                 // 0..7
    const int l   = tid & 63;
    const int rowbase = (int)blockIdx.x * 64;

    // staging map
    const int sr = tid >> 3;                  // 0..63 (row)
    const int kq = tid & 7;                   // 0..7  (8-float chunk in 64-k period)
    const float* appsrc = app + (size_t)(rowbase + sr) * 1024 + kq * 8;
    const float* spsrc  = sp  + (size_t)(rowbase + sr) * 512  + kq * 8;
    unsigned short* as0 = &sh.As[0][kq >> 2][sr >> 4][(kq & 3) * 16 + (sr & 15)][0];
    unsigned short* as1 = &sh.As[1][kq >> 2][sr >> 4][(kq & 3) * 16 + (sr & 15)][0];

    floatx4 acc[4][4];
    #pragma unroll
    for (int mt = 0; mt < 4; ++mt)
        #pragma unroll
        for (int nt = 0; nt < 4; ++nt)
            acc[mt][nt] = (floatx4){0.f, 0.f, 0.f, 0.f};

    const unsigned short* wbase = wcat + (size_t)w * 2048 + (size_t)l * 8;

    // prologue: load+stage period 0; load B-frags for period 0
    bf16x8 bcur[8];
    #pragma unroll
    for (int i = 0; i < 8; ++i)
        bcur[i] = *(const bf16x8*)(wbase + (i >> 2) * 16384 + (i & 3) * 512);
    {
        float4 q0 = *(const float4*)(appsrc);
        float4 q1 = *(const float4*)(appsrc + 4);
        union { unsigned short us[8]; int4 v; } pk;
        pk.us[0] = f2bf(q0.x); pk.us[1] = f2bf(q0.y); pk.us[2] = f2bf(q0.z); pk.us[3] = f2bf(q0.w);
        pk.us[4] = f2bf(q1.x); pk.us[5] = f2bf(q1.y); pk.us[6] = f2bf(q1.z); pk.us[7] = f2bf(q1.w);
        *(int4*)as0 = pk.v;
    }
    asm volatile("s_waitcnt lgkmcnt(0)" ::: "memory");
    __builtin_amdgcn_s_barrier();

    // ---- phase 1: H_pre = [app|sp] @ Wcat, K = 1536 (24 periods of 64) ----
    for (int p = 0; p < 24; ++p) {
        const int buf = p & 1;
        unsigned short* dst = buf ? as0 : as1;          // stage target (p+1)

        // issue HBM A-loads for period p+1 (consumed at tail of this period)
        float4 pA0, pA1;
        if (p + 1 < 24) {
            const float* src = (p + 1 < 16) ? (appsrc + (p + 1) * 64)
                                            : (spsrc + (p - 15) * 64);
            pA0 = *(const float4*)src;
            pA1 = *(const float4*)(src + 4);
        }

        bf16x8 af[4];
        // half 0 (k = p*64 .. +31)
        #pragma unroll
        for (int mt = 0; mt < 4; ++mt)
            af[mt] = *(const bf16x8*)(&sh.As[buf][0][mt][l][0]);
        __builtin_amdgcn_s_setprio(1);
        #pragma unroll
        for (int mt = 0; mt < 4; ++mt)
            #pragma unroll
            for (int nt = 0; nt < 4; ++nt)
                acc[mt][nt] = __builtin_amdgcn_mfma_f32_16x16x32_bf16(
                    af[mt], bcur[nt], acc[mt][nt], 0, 0, 0);
        __builtin_amdgcn_s_setprio(0);
        // half 1 (k = p*64+32 .. +63)
        #pragma unroll
        for (int mt = 0; mt < 4; ++mt)
            af[mt] = *(const bf16x8*)(&sh.As[buf][1][mt][l][0]);
        __builtin_amdgcn_s_setprio(1);
        #pragma unroll
        for (int mt = 0; mt < 4; ++mt)
            #pragma unroll
            for (int nt = 0; nt < 4; ++nt)
                acc[mt][nt] = __builtin_amdgcn_mfma_f32_16x16x32_bf16(
                    af[mt], bcur[4 + nt], acc[mt][nt], 0, 0, 0);
        __builtin_amdgcn_s_setprio(0);

        // batched B-frag reload for p+1 (in flight across tail+barrier+reads)
        if (p + 1 < 24) {
            const unsigned short* wp = wbase + (size_t)(p + 1) * 32768;
            #pragma unroll
            for (int i = 0; i < 8; ++i)
                bcur[i] = *(const bf16x8*)(wp + (i >> 2) * 16384 + (i & 3) * 512);
            // stage A chunk p+1 (waits only its own vmcnt, counted)
            union { unsigned short us[8]; int4 v; } pk;
            pk.us[0] = f2bf(pA0.x); pk.us[1] = f2bf(pA0.y); pk.us[2] = f2bf(pA0.z); pk.us[3] = f2bf(pA0.w);
            pk.us[4] = f2bf(pA1.x); pk.us[5] = f2bf(pA1.y); pk.us[6] = f2bf(pA1.z); pk.us[7] = f2bf(pA1.w);
            *(int4*)dst = pk.v;
        }

        asm volatile("s_waitcnt lgkmcnt(0)" ::: "memory");
        __builtin_amdgcn_s_barrier();
    }

    // ---- phase-3 W3 prefetch (before phase-2 barrier; vmcnt survives) ----
    const unsigned short* w3base = w3f + (size_t)w * 2048 + (size_t)l * 8;
    bf16x8 b3[8];
    #pragma unroll
    for (int i = 0; i < 8; ++i)
        b3[i] = *(const bf16x8*)(w3base + (i >> 2) * 16384 + (i & 3) * 512);

    // ---- phase 2: relu + bias, write Hf in A-frag layout (clobbers As) ----
    #pragma unroll
    for (int nt = 0; nt < 4; ++nt) {
        const int colg = w * 64 + nt * 16 + (l & 15);
        const float bv = bias12[colg];
        const int kc  = colg >> 5;
        const int lhi = ((colg >> 3) & 3) << 4;
        const int j   = colg & 7;
        #pragma unroll
        for (int mt = 0; mt < 4; ++mt)
            #pragma unroll
            for (int r = 0; r < 4; ++r) {
                const int rlow = ((l >> 4) << 2) + r;      // rowg & 15
                float v = acc[mt][nt][r] + bv;
                v = fmaxf(v, 0.f);
                sh.Hf[mt][kc][lhi + rlow][j] = f2bf(v);
            }
    }
    asm volatile("s_waitcnt lgkmcnt(0)" ::: "memory");
    __builtin_amdgcn_s_barrier();

    // ---- phase 3: out = relu(Hf @ W3 + bias3s), K = 512, NO barriers ----
    #pragma unroll
    for (int mt = 0; mt < 4; ++mt)
        #pragma unroll
        for (int nt = 0; nt < 4; ++nt)
            acc[mt][nt] = (floatx4){0.f, 0.f, 0.f, 0.f};

    for (int q = 0; q < 8; ++q) {
        bf16x8 af[4];
        #pragma unroll
        for (int mt = 0; mt < 4; ++mt)
            af[mt] = *(const bf16x8*)(&sh.Hf[mt][2 * q][l][0]);
        __builtin_amdgcn_s_setprio(1);
        #pragma unroll
        for (int mt = 0; mt < 4; ++mt)
            #pragma unroll
            for (int nt = 0; nt < 4; ++nt)
                acc[mt][nt] = __builtin_amdgcn_mfma_f32_16x16x32_bf16(
                    af[mt], b3[nt], acc[mt][nt], 0, 0, 0);
        __builtin_amdgcn_s_setprio(0);
        #pragma unroll
        for (int mt = 0; mt < 4; ++mt)
            af[mt] = *(const bf16x8*)(&sh.Hf[mt][2 * q + 1][l][0]);
        __builtin_amdgcn_s_setprio(1);
        #pragma unroll
        for (int mt = 0; mt < 4; ++mt)
            #pragma unroll
            for (int nt = 0; nt < 4; ++nt)
                acc[mt][nt] = __builtin_amdgcn_mfma_f32_16x16x32_bf16(
                    af[mt], b3[4 + nt], acc[mt][nt], 0, 0, 0);
        __builtin_amdgcn_s_setprio(0);
        if (q + 1 < 8) {
            const unsigned short* wp = w3base + (size_t)(q + 1) * 32768;
            #pragma unroll
            for (int i = 0; i < 8; ++i)
                b3[i] = *(const bf16x8*)(wp + (i >> 2) * 16384 + (i & 3) * 512);
        }
    }

    // ---- epilogue ----
    #pragma unroll
    for (int nt = 0; nt < 4; ++nt) {
        const int colg = w * 64 + nt * 16 + (l & 15);
        const float bv = bias3s[colg];
        #pragma unroll
        for (int mt = 0; mt < 4; ++mt)
            #pragma unroll
            for (int r = 0; r < 4; ++r) {
                const int rowg = mt * 16 + ((l >> 4) << 2) + r;
                float v = acc[mt][nt][r] + bv;
                v = fmaxf(v, 0.f);
                out[(size_t)(rowbase + rowg) * 512 + colg] = v;
            }
    }
}

extern "C" void kernel_launch(void* const* d_in, const int* in_sizes, int n_in,
                              void* d_out, int out_size, void* d_ws, size_t ws_size,
                              hipStream_t stream)
{
    const float* app = (const float*)d_in[0];
    const float* sp  = (const float*)d_in[1];
    const float* W1  = (const float*)d_in[2];
    const float* b1  = (const float*)d_in[3];
    const float* W2  = (const float*)d_in[4];
    const float* b2  = (const float*)d_in[5];
    const float* W3  = (const float*)d_in[6];
    const float* b3  = (const float*)d_in[7];

    char* ws = (char*)d_ws;
    unsigned short* wcat  = (unsigned short*)(ws);             // 1,572,864 B
    unsigned short* w3f   = (unsigned short*)(ws + 1572864);   //   524,288 B
    float*          b12   = (float*)(ws + 2097152);            //     2,048 B
    float*          b3s   = (float*)(ws + 2099200);            //     2,048 B

    prep_kernel<<<514, 256, 0, stream>>>(W1, b1, W2, b2, W3, b3, wcat, w3f, b12, b3s);

    float* outp = (float*)d_out;
    fused_main<<<65536 / 64, 512, 0, stream>>>(app, sp, wcat, w3f, b12, b3s, outp);
}